// Round 11
// baseline (612.413 us; speedup 1.0000x reference)
//
#include <hip/hip_runtime.h>

// TurboFlashAttention: causal B=2,H=16,S=2048,D=64 fp32 + 512MB zero placeholder.
// R16: occupancy 2->3 waves/SIMD + concurrent fill in the 3rd CU slot.
// Ledger R5-R15: every intra-slot fix is neutral; compute wall ~150us vs
// ~15us/SIMD issue work (10x stall) with only 2 waves/SIMD resident. R16 is
// the unconfounded R11: keep R12's proven-safe grid (512 compute blocks first,
// then 1024 x 512KiB pure-fill blocks), add launch_bounds(256,3) (VGPR cap
// 170; natural usage ~150 by count -> expect no spills) and shave all LDS
// pads 72->68 (total 52,224 B <= 53,333 = 160KiB/3). Fill blocks now occupy
// the 3rd resident slot and stream in SEPARATE waves (m114: wave-level pipe
// overlap), while compute gets 3 waves/SIMD of latency hiding.
// Outcome decodes: ~520-550 = occupancy theory confirmed; ~620+ = cap-170
// spills (diagnoses R11); ~585 = per-wave chain is serial -> plateau.
// Keeps: R15 permlane softmax, vrow V^T staging, raw lgkm barrier, setprio,
// interleave s-map, 2-deep prefetch dbuf.

typedef __bf16 bf16x8 __attribute__((ext_vector_type(8)));
typedef float f32x4 __attribute__((ext_vector_type(4)));

#define LOG2E 1.44269504088896340736f

__device__ __forceinline__ unsigned short f2bf(float f) {
  unsigned int u = __float_as_uint(f);
  u += 0x7fffu + ((u >> 16) & 1u);   // RNE
  return (unsigned short)(u >> 16);
}

// Cross-wave LDS sync WITHOUT the vmcnt(0) drain __syncthreads would emit.
__device__ __forceinline__ void block_sync_lds() {
  asm volatile("s_waitcnt lgkmcnt(0)" ::: "memory");
  __builtin_amdgcn_s_barrier();
}

// xor-16 / xor-32 butterfly reduce at VALU speed (gfx950 permlane*_swap).
// Empty asm on b forces a DISTINCT VGPR (R14 bug: coalesced self-swap).
__device__ __forceinline__ float redmax_q(float x) {
  float a = x, b = x;
  asm volatile("" : "+v"(b));
  asm("v_permlane16_swap_b32 %0, %1" : "+v"(a), "+v"(b));
  float m = fmaxf(a, b);
  float c = m, d = m;
  asm volatile("" : "+v"(d));
  asm("v_permlane32_swap_b32 %0, %1" : "+v"(c), "+v"(d));
  return fmaxf(c, d);
}
__device__ __forceinline__ float redsum_q(float x) {
  float a = x, b = x;
  asm volatile("" : "+v"(b));
  asm("v_permlane16_swap_b32 %0, %1" : "+v"(a), "+v"(b));
  float s = a + b;
  float c = s, d = s;
  asm volatile("" : "+v"(d));
  asm("v_permlane32_swap_b32 %0, %1" : "+v"(c), "+v"(d));
  return c + d;
}

constexpr int Sdim = 2048, Ddim = 64, BHn = 32;
constexpr int STiles = 16;                   // 128-row q-supertiles
constexpr int LDA = 68;                      // LDS leading-dim pad (shorts)
constexpr int OUT0 = BHn * Sdim * Ddim;      // output-region floats
constexpr int NCOMPUTE = BHn * STiles;       // 512 compute blocks
constexpr int NFILL = 1024;                  // 512 KiB fill blocks
constexpr size_t FILL_F4_PER_BLK = 32768;    // 512 KiB in f32x4; 1024 blks = 512 MiB

__device__ __forceinline__ int vswz_m(int d) { return ((d >> 2) ^ (d >> 5)) & 7; }
// physical V^T row permutation: bijective within each 8-row block.
__device__ __forceinline__ int vrow(int d) { return (d & 56) | ((d ^ (d >> 3)) & 7); }

__global__ __launch_bounds__(256, 3)
void flash_causal_kernel(const float* __restrict__ Q, const float* __restrict__ K,
                         const float* __restrict__ V, float* __restrict__ out) {
  __shared__ unsigned short Klds[2][64 * LDA];      // K tile [kn][d]      17,408 B
  __shared__ unsigned short Vlds[2][64 * LDA];      // V^T [vrow(d)][kn^s] 17,408 B
  __shared__ unsigned short Plds[4][2][16 * LDA];   // per-wave P^T        17,408 B

  const int tid = threadIdx.x;
  const int b   = (int)blockIdx.x;

  // ---- fill blocks (b >= 512): occupy 3rd CU slots / backfill retired ones.
  if (b >= NCOMPUTE) {
    const int fidx = b - NCOMPUTE;                 // 0..1023
    f32x4* zp = (f32x4*)(out + OUT0) + (size_t)fidx * FILL_F4_PER_BLK;
    const f32x4 z4 = (f32x4){0.f, 0.f, 0.f, 0.f};
    #pragma unroll 4
    for (size_t i = tid; i < FILL_F4_PER_BLK; i += 256)
      __builtin_nontemporal_store(z4, zp + i);
    return;
  }

  const int wave = tid >> 6;
  const int lane = tid & 63;
  const int quad = lane >> 4;
  const int l15  = lane & 15;

  const int bh = b & (BHn - 1);
  const int g  = b >> 5;                                        // 0..15
  const int s  = (g & 1) ? (STiles - 1) - (g >> 1) : (g >> 1);  // interleave
  const int jmax = 2 * s + 1;

  const int base  = bh * Sdim * Ddim;
  const int qbase = s * 128;

  // ---- Q fragments (B-operand), scale 1/8 folded. frag f: rows qbase+64f+16w.
  bf16x8 aq[2][2];
  #pragma unroll
  for (int f = 0; f < 2; ++f) {
    const float* qp = Q + base + (qbase + 64 * f + wave * 16 + l15) * Ddim + quad * 8;
    #pragma unroll
    for (int s2 = 0; s2 < 2; ++s2) {
      float4 a = *(const float4*)(qp + 32 * s2);
      float4 bq = *(const float4*)(qp + 32 * s2 + 4);
      union { unsigned short u[8]; bf16x8 v; } u;
      u.u[0] = f2bf(a.x * 0.125f);  u.u[1] = f2bf(a.y * 0.125f);
      u.u[2] = f2bf(a.z * 0.125f);  u.u[3] = f2bf(a.w * 0.125f);
      u.u[4] = f2bf(bq.x * 0.125f); u.u[5] = f2bf(bq.y * 0.125f);
      u.u[6] = f2bf(bq.z * 0.125f); u.u[7] = f2bf(bq.w * 0.125f);
      aq[f][s2] = u.v;
    }
  }

  f32x4 ot[2][4];
  #pragma unroll
  for (int f = 0; f < 2; ++f)
    #pragma unroll
    for (int t = 0; t < 4; ++t) ot[f][t] = (f32x4){0.f, 0.f, 0.f, 0.f};
  float mrun[2] = {-__builtin_inff(), -__builtin_inff()};
  float lrun[2] = {0.f, 0.f};

  const float4* kg4 = (const float4*)(K + base);
  const float4* vg4 = (const float4*)(V + base);
  float4 kf[4], vf[4];

  auto ldtile = [&](int j) {
    const float4* kp = kg4 + j * 1024;
    const float4* vp = vg4 + j * 1024;
    #pragma unroll
    for (int i = 0; i < 4; ++i) { kf[i] = kp[i * 256 + tid]; vf[i] = vp[i * 256 + tid]; }
  };
  auto stage = [&](int buf) {
    #pragma unroll
    for (int i = 0; i < 4; ++i) {
      int lin = i * 256 + tid;
      int row = lin >> 4;
      int c4  = (lin & 15) << 2;
      uint2 t2;
      t2.x = (unsigned int)f2bf(kf[i].x) | ((unsigned int)f2bf(kf[i].y) << 16);
      t2.y = (unsigned int)f2bf(kf[i].z) | ((unsigned int)f2bf(kf[i].w) << 16);
      *(uint2*)&Klds[buf][row * LDA + c4] = t2;
      const int sw = vswz_m(c4) << 3;   // vswz_m constant over c4..c4+3
      Vlds[buf][vrow(c4 + 0) * LDA + (row ^ sw)] = f2bf(vf[i].x);
      Vlds[buf][vrow(c4 + 1) * LDA + (row ^ sw)] = f2bf(vf[i].y);
      Vlds[buf][vrow(c4 + 2) * LDA + (row ^ sw)] = f2bf(vf[i].z);
      Vlds[buf][vrow(c4 + 3) * LDA + (row ^ sw)] = f2bf(vf[i].w);
    }
  };

  // ---- prologue
  ldtile(0); stage(0); ldtile(1);   // jmax >= 1 always

  for (int j = 0; j <= jmax; ++j) {
    block_sync_lds();
    if (j < jmax) stage((j + 1) & 1);
    if (j + 2 <= jmax) ldtile(j + 2);

    const unsigned short* Kb = Klds[j & 1];
    const unsigned short* Vb = Vlds[j & 1];
    const bool f0act = (j <= 2 * s);   // frag0 has no columns at j == jmax

    // ---- S^T for both frags; K fragment read once, used twice
    f32x4 sc[2][4];
    #pragma unroll
    for (int f = 0; f < 2; ++f)
      #pragma unroll
      for (int t = 0; t < 4; ++t) sc[f][t] = (f32x4){0.f, 0.f, 0.f, 0.f};
    __builtin_amdgcn_s_setprio(1);
    #pragma unroll
    for (int s2 = 0; s2 < 2; ++s2) {
      #pragma unroll
      for (int t = 0; t < 4; ++t) {
        bf16x8 ka = *(const bf16x8*)&Kb[(16 * t + l15) * LDA + 32 * s2 + quad * 8];
        sc[0][t] = __builtin_amdgcn_mfma_f32_16x16x32_bf16(ka, aq[0][s2], sc[0][t], 0, 0, 0);
        sc[1][t] = __builtin_amdgcn_mfma_f32_16x16x32_bf16(ka, aq[1][s2], sc[1][t], 0, 0, 0);
      }
    }
    __builtin_amdgcn_s_setprio(0);

    // ---- causal diagonal masks (frag f diag at j == 2s+f; local coords equal)
    #pragma unroll
    for (int f = 0; f < 2; ++f) {
      if (j == 2 * s + f) {
        const int qml = wave * 16 + l15;
        #pragma unroll
        for (int t = 0; t < 4; ++t)
          #pragma unroll
          for (int r = 0; r < 4; ++r)
            if (16 * t + 4 * quad + r > qml) sc[f][t][r] = -__builtin_inff();
      }
    }

    // ---- online softmax + P write (per frag; frag0 skipped on final odd iter)
    #pragma unroll
    for (int f = 0; f < 2; ++f) {
      if (f == 0 && !f0act) continue;
      float tmx[4];
      #pragma unroll
      for (int t = 0; t < 4; ++t)
        tmx[t] = fmaxf(fmaxf(sc[f][t][0], sc[f][t][1]),
                       fmaxf(sc[f][t][2], sc[f][t][3]));
      float mx = fmaxf(fmaxf(tmx[0], tmx[1]), fmaxf(tmx[2], tmx[3]));
      mx = redmax_q(mx);
      float mn    = fmaxf(mrun[f], mx);
      float alpha = __builtin_amdgcn_exp2f((mrun[f] - mn) * LOG2E);
      float msc   = mn * LOG2E;
      mrun[f] = mn;
      float rsp[4];
      #pragma unroll
      for (int t = 0; t < 4; ++t) {
        float p0 = __builtin_amdgcn_exp2f(fmaf(sc[f][t][0], LOG2E, -msc));
        float p1 = __builtin_amdgcn_exp2f(fmaf(sc[f][t][1], LOG2E, -msc));
        float p2 = __builtin_amdgcn_exp2f(fmaf(sc[f][t][2], LOG2E, -msc));
        float p3 = __builtin_amdgcn_exp2f(fmaf(sc[f][t][3], LOG2E, -msc));
        sc[f][t][0] = p0; sc[f][t][1] = p1; sc[f][t][2] = p2; sc[f][t][3] = p3;
        rsp[t] = (p0 + p1) + (p2 + p3);
      }
      float rs = (rsp[0] + rsp[1]) + (rsp[2] + rsp[3]);
      rs = redsum_q(rs);
      lrun[f] = lrun[f] * alpha + rs;
      #pragma unroll
      for (int t = 0; t < 4; ++t) {
        uint2 pw;
        pw.x = (unsigned int)f2bf(sc[f][t][0]) | ((unsigned int)f2bf(sc[f][t][1]) << 16);
        pw.y = (unsigned int)f2bf(sc[f][t][2]) | ((unsigned int)f2bf(sc[f][t][3]) << 16);
        *(uint2*)&Plds[wave][f][l15 * LDA + 16 * t + 4 * quad] = pw;
      }
      #pragma unroll
      for (int t = 0; t < 4; ++t)
        #pragma unroll
        for (int r = 0; r < 4; ++r) ot[f][t][r] *= alpha;
    }

    // ---- O^T += V^T * P^T; V fragment read once, used for both frags
    __builtin_amdgcn_s_setprio(1);
    #pragma unroll
    for (int s2 = 0; s2 < 2; ++s2) {
      bf16x8 pb0, pb1;
      if (f0act) pb0 = *(const bf16x8*)&Plds[wave][0][l15 * LDA + 32 * s2 + quad * 8];
      pb1 = *(const bf16x8*)&Plds[wave][1][l15 * LDA + 32 * s2 + quad * 8];
      #pragma unroll
      for (int t = 0; t < 4; ++t) {
        const int d = 16 * t + l15;
        bf16x8 va = *(const bf16x8*)&Vb[vrow(d) * LDA + (((4 * s2 + quad) ^ vswz_m(d)) << 3)];
        if (f0act)
          ot[0][t] = __builtin_amdgcn_mfma_f32_16x16x32_bf16(va, pb0, ot[0][t], 0, 0, 0);
        ot[1][t] = __builtin_amdgcn_mfma_f32_16x16x32_bf16(va, pb1, ot[1][t], 0, 0, 0);
      }
    }
    __builtin_amdgcn_s_setprio(0);
  }

  // ---- epilogue (no tail fill: fill lives entirely in the fill blocks)
  #pragma unroll
  for (int f = 0; f < 2; ++f) {
    float inv = 1.0f / lrun[f];
    float* orow = out + base + (qbase + 64 * f + wave * 16 + l15) * Ddim + 4 * quad;
    #pragma unroll
    for (int t = 0; t < 4; ++t) {
      f32x4 o4;
      o4.x = ot[f][t][0] * inv; o4.y = ot[f][t][1] * inv;
      o4.z = ot[f][t][2] * inv; o4.w = ot[f][t][3] * inv;
      *(f32x4*)(orow + 16 * t) = o4;
    }
  }
}

extern "C" void kernel_launch(void* const* d_in, const int* in_sizes, int n_in,
                              void* d_out, int out_size, void* d_ws, size_t ws_size,
                              hipStream_t stream) {
  const float* q = (const float*)d_in[0];
  const float* k = (const float*)d_in[1];
  const float* v = (const float*)d_in[2];
  float* out = (float*)d_out;
  // 512 compute blocks (2/CU) + 1024 x 512KiB fill blocks that occupy the
  // 3rd resident slot per CU (LDS 52,224 B x3 <= 160KiB; VGPR cap 170).
  dim3 grid(NCOMPUTE + NFILL);
  flash_causal_kernel<<<grid, dim3(256), 0, stream>>>(q, k, v, out);
}